// Round 4
// baseline (432.327 us; speedup 1.0000x reference)
//
#include <hip/hip_runtime.h>
#include <hip/hip_bf16.h>

// EdgeDecoder: out[e] = w2 . relu(W1 @ concat(z_sotu[row[e]], z_taxon[col[e]]) + b1) + b2
// E=1e6, H=128, K=2H=256. fp32 inputs, int32 indices, fp32 output.
//
// Round 4: the kernel is gather-LATENCY-bound (R2: 42% busy, R3: 25% busy, both slow;
// occupancy only 21%). Fix = TLP: 512-thread blocks (8 waves), TILE_E=128, 64 KB LDS
// -> still 2 blocks/CU but 16 waves/CU (2x latency hiding). Staging is the proven
// round-2 coalesced fp32 gather + packed bf16 convert + XOR-swizzled ds_write
// (global_load_lds DMA regressed: scattered per-lane 16B requests + vmcnt(0) drain).
//
// GEMM: C[M=128 hidden][N=128 edges] = W1 @ Z^T, mfma_f32_32x32x16_bf16.
// Wave w: mg=w&3 owns hidden rows [32mg,32mg+32) (A-frags in 64 VGPRs),
//         ng=w>>2 owns edge n-tiles {2ng, 2ng+1} (acc = 2x16 AGPRs).
// Unified VGPR+AGPR ~110 <= 128 enforced by __launch_bounds__(512,4) -> 4 waves/SIMD.
// Epilogue: in-lane relu+fma (C layout col=lane&31=edge), shfl_xor(32) merges the
// complementary 16 hidden of the same edge, 4 mg-partials combined via 2 KB LDS.

#define HID    128
#define KDIM   256
#define TILE_E 128

typedef __attribute__((ext_vector_type(8)))  short    bf16x8;   // 8 bf16 = 4 VGPRs
typedef __attribute__((ext_vector_type(16))) float    f32x16;   // 32x32 MFMA accumulator
typedef __attribute__((ext_vector_type(4)))  unsigned uint4v;   // 16 B

__device__ __forceinline__ unsigned pk2(float x, float y) {
    __hip_bfloat162 t = __float22bfloat162_rn(make_float2(x, y));  // RNE, packed cvt
    return *reinterpret_cast<unsigned*>(&t);
}
__device__ __forceinline__ uint4v pack8u(float4 a, float4 b) {
    uint4v r;
    r.x = pk2(a.x, a.y); r.y = pk2(a.z, a.w);
    r.z = pk2(b.x, b.y); r.w = pk2(b.z, b.w);
    return r;
}

__global__ __launch_bounds__(512, 4)
void edge_mlp_kernel(const float* __restrict__ z_sotu,   // [100000,128] fp32
                     const float* __restrict__ z_taxon,  // [50000,128] fp32
                     const int*   __restrict__ row,      // [E] int32
                     const int*   __restrict__ col,      // [E] int32
                     const float* __restrict__ w1,       // [128,256] fp32
                     const float* __restrict__ b1,       // [128]
                     const float* __restrict__ w2,       // [128]
                     const float* __restrict__ b2,       // [1]
                     float*       __restrict__ out,      // [E] fp32
                     int E)
{
    __shared__ __align__(16) unsigned short zs[TILE_E * KDIM];   // 64 KB bf16, swizzled

    const int tid  = threadIdx.x;
    const int wave = tid >> 6;       // 0..7
    const int lane = tid & 63;
    const int l31  = lane & 31;
    const int hlf  = lane >> 5;
    const int mg   = wave & 3;       // hidden group: rows [32mg, 32mg+32)
    const int ng   = wave >> 2;      // edge half: n-tiles {2ng, 2ng+1}
    const long long e0 = (long long)blockIdx.x * TILE_E;

    // ---- Stage Z tile: wave w stages tile rows [16w, 16w+16) (= 32 row-halves).
    // lane = rhl*16 + ch: 16 lanes cover one contiguous 512 B fp32 row-half (coalesced);
    // 8 passes x 4 row-halves. Chunk c (8 floats -> 8 bf16 = 16 B) stored XOR-swizzled
    // at position q = c ^ (r&31) so K-loop ds_read_b128 is conflict-free (R2-verified: 0).
    {
        const int ch  = lane & 15;     // chunk within row-half
        const int rhl = lane >> 4;     // row-half within pass (0..3)
        #pragma unroll
        for (int pass = 0; pass < 8; ++pass) {
            const int rh = pass * 4 + rhl;          // row-half within wave slice (0..31)
            const int r  = 16 * wave + (rh >> 1);   // tile row (= edge slot)
            const int hh = rh & 1;                  // 0 = sotu half, 1 = taxon half
            long long e = e0 + r;
            if (e >= E) e = E - 1;                  // tail clamp (store is guarded)
            const int idx = hh ? col[e] : row[e];
            const float* src = (hh ? z_taxon : z_sotu) + (long long)idx * HID + ch * 8;
            const float4 a = *(const float4*)(src);
            const float4 b = *(const float4*)(src + 4);
            const int c = hh * 16 + ch;             // chunk index in concat row (0..31)
            const int q = c ^ (r & 31);             // swizzled position
            *(uint4v*)(zs + r * KDIM + q * 8) = pack8u(a, b);
        }
    }

    // ---- W1 A-frags for hidden group mg (fp32 -> bf16; W1 is L2-hot).
    // A layout: lane holds A[m=lane&31][k = hlf*8 + j]; frag ks covers k = 16*ks..+16.
    bf16x8 afrag[16];
    {
        const float* wrow = w1 + (32 * mg + l31) * KDIM + hlf * 8;
        #pragma unroll
        for (int ks = 0; ks < 16; ++ks) {
            const float4 a = *(const float4*)(wrow + ks * 16);
            const float4 b = *(const float4*)(wrow + ks * 16 + 4);
            uint4v t = pack8u(a, b);
            afrag[ks] = *reinterpret_cast<bf16x8*>(&t);
        }
    }
    __syncthreads();

    // ---- K-loop: 2 n-tiles x 16 k-steps = 32 MFMAs/wave.
    // B layout: lane holds B[n=lane&31][k=hlf*8+j]; chunk c = 2ks+hlf at pos c^l31.
    const int ntb = ng * 2;
    f32x16 acc[2] = {};
    #pragma unroll
    for (int ks = 0; ks < 16; ++ks) {
        #pragma unroll
        for (int t = 0; t < 2; ++t) {
            const int el = 32 * (ntb + t) + l31;          // edge slot within tile
            const int q  = (2 * ks + hlf) ^ l31;          // swizzled chunk position
            bf16x8 bfrag = *(const bf16x8*)(zs + el * KDIM + q * 8);
            acc[t] = __builtin_amdgcn_mfma_f32_32x32x16_bf16(afrag[ks], bfrag, acc[t], 0, 0, 0);
        }
    }

    __syncthreads();                  // all b-frag reads done before aliasing zs
    float* partial = (float*)zs;      // [4 mg][TILE_E] cross-wave partials (2 KB)

    // b1/w2 for this lane's 16 hidden rows: hid = 32mg + (r&3) + 8*(r>>2) + 4*hlf
    float b1v[16], w2v[16];
    #pragma unroll
    for (int g = 0; g < 4; ++g) {
        const int hb = 32 * mg + 8 * g + 4 * hlf;
        const float4 bb = *(const float4*)(b1 + hb);
        const float4 ww = *(const float4*)(w2 + hb);
        b1v[4*g+0] = bb.x; b1v[4*g+1] = bb.y; b1v[4*g+2] = bb.z; b1v[4*g+3] = bb.w;
        w2v[4*g+0] = ww.x; w2v[4*g+1] = ww.y; w2v[4*g+2] = ww.z; w2v[4*g+3] = ww.w;
    }

    // Lane holds 16 hidden of edge (32*(ntb+t) + l31); mirror lane (^32) holds the
    // complementary 16 of the SAME edge -> one shfl_xor completes this mg's 32-hid slice.
    #pragma unroll
    for (int t = 0; t < 2; ++t) {
        float p = 0.0f;
        #pragma unroll
        for (int r = 0; r < 16; ++r) {
            const float h = fmaxf(acc[t][r] + b1v[r], 0.0f);
            p = fmaf(h, w2v[r], p);
        }
        p += __shfl_xor(p, 32, 64);
        if (hlf == 0)
            partial[mg * TILE_E + 32 * (ntb + t) + l31] = p;
    }
    __syncthreads();

    if (tid < TILE_E) {
        const long long e = e0 + tid;
        if (e < E) {
            out[e] = partial[0 * TILE_E + tid] + partial[1 * TILE_E + tid]
                   + partial[2 * TILE_E + tid] + partial[3 * TILE_E + tid]
                   + b2[0];
        }
    }
}

extern "C" void kernel_launch(void* const* d_in, const int* in_sizes, int n_in,
                              void* d_out, int out_size, void* d_ws, size_t ws_size,
                              hipStream_t stream) {
    const float* z_sotu  = (const float*)d_in[0];
    const float* z_taxon = (const float*)d_in[1];
    const int*   row     = (const int*)d_in[2];
    const int*   col     = (const int*)d_in[3];
    const float* w1      = (const float*)d_in[4];
    const float* b1      = (const float*)d_in[5];
    const float* w2      = (const float*)d_in[6];
    const float* b2      = (const float*)d_in[7];
    float*       out     = (float*)d_out;

    const int E = in_sizes[2];
    const int nblocks = (E + TILE_E - 1) / TILE_E;
    hipLaunchKernelGGL(edge_mlp_kernel, dim3(nblocks), dim3(512), 0, stream,
                       z_sotu, z_taxon, row, col, w1, b1, w2, b2, out, E);
}

// Round 5
// 233.846 us; speedup vs baseline: 1.8488x; 1.8488x over previous
//
#include <hip/hip_runtime.h>
#include <hip/hip_bf16.h>

// EdgeDecoder: out[e] = w2 . relu(W1 @ concat(z_sotu[row[e]], z_taxon[col[e]]) + b1) + b2
// E=1e6, H=128, K=2H=256. fp32 inputs, int32 indices, fp32 output.
//
// Round 5: kernel is gather-latency-bound (R2-R4: VALU-work ~62us-eq, MFMA ~27us-eq,
// constant; rest is idle). R4 lesson: launch_bounds(512,4) strangled regs -> compiler
// sank afrag loads into the K-loop (VGPR_Count 56 < afrag's 64). Fixes here:
//  1. bf16 pre-pass (convert_kernel) -> gather bytes halve, staging is load->ds_write
//     with no cvt chain (12 loads in flight), afrag = plain bf16 loads.
//  2. TILE_E=96 -> LDS 48 KB -> 3 blocks/CU; acc 48 regs; combined ~150 fits
//     launch_bounds(256,3)'s 170 cap with headroom -> 12 waves/CU (1.5x R2 TLP).
//  3. Indices pre-loaded ahead of the gather loop (breaks idx->gather serial chains).
//
// GEMM: C[M=128 hidden][N=96 edges] = W1 @ Z^T, mfma_f32_32x32x16_bf16.
// Wave w owns hidden rows [32w,32w+32) (afrag 64 VGPRs), iterates 3 edge n-tiles.
// XOR swizzle (slot q = c ^ (r&31)) -> ds_read_b128/ds_write_b128 conflict-free
// (0 measured in R2/R4). Epilogue: in-lane relu+dot, shfl_xor(32), 1.5 KB LDS combine.

#define HID  128
#define KDIM 256
#define TE   96     // main-kernel edge tile
#define FTE  128    // fallback tile

typedef __attribute__((ext_vector_type(8)))  short    bf16x8;   // 8 bf16 = 4 VGPRs
typedef __attribute__((ext_vector_type(16))) float    f32x16;   // 32x32 MFMA accumulator
typedef __attribute__((ext_vector_type(4)))  unsigned uint4v;   // 16 B

__device__ __forceinline__ unsigned pk2(float x, float y) {
    __hip_bfloat162 t = __float22bfloat162_rn(make_float2(x, y));  // packed RNE cvt
    return *reinterpret_cast<unsigned*>(&t);
}
__device__ __forceinline__ uint4v pack8u(float4 a, float4 b) {
    uint4v r;
    r.x = pk2(a.x, a.y); r.y = pk2(a.z, a.w);
    r.z = pk2(b.x, b.y); r.w = pk2(b.z, b.w);
    return r;
}

// ---------------- Phase 1: fp32 -> bf16 bulk convert (16 elems/thread, coalesced)
__global__ __launch_bounds__(256)
void convert_kernel(const float* __restrict__ s, const float* __restrict__ t,
                    const float* __restrict__ w,
                    unsigned short* __restrict__ os, unsigned short* __restrict__ ot,
                    unsigned short* __restrict__ ow,
                    long long ES, long long ET, long long EW)
{
    const long long i16 = ((long long)blockIdx.x * 256 + threadIdx.x) * 16;
    const long long total = ES + ET + EW;        // all regions divisible by 16
    if (i16 >= total) return;
    const float* src; unsigned short* dst; long long off;
    if (i16 < ES)           { src = s; dst = os; off = i16; }
    else if (i16 < ES + ET) { src = t; dst = ot; off = i16 - ES; }
    else                    { src = w; dst = ow; off = i16 - ES - ET; }
    const float4 a = *(const float4*)(src + off);
    const float4 b = *(const float4*)(src + off + 4);
    const float4 c = *(const float4*)(src + off + 8);
    const float4 d = *(const float4*)(src + off + 12);
    *(uint4v*)(dst + off)     = pack8u(a, b);
    *(uint4v*)(dst + off + 8) = pack8u(c, d);
}

// ---------------- Phase 2: hot kernel — bf16 gather, TILE 96, 3 blocks/CU
__global__ __launch_bounds__(256, 3)
void edge_mlp_kernel(const unsigned short* __restrict__ zsb,  // [100000,128] bf16
                     const unsigned short* __restrict__ ztb,  // [50000,128] bf16
                     const int*   __restrict__ row,           // [E] int32
                     const int*   __restrict__ col,           // [E] int32
                     const unsigned short* __restrict__ w1b,  // [128,256] bf16
                     const float* __restrict__ b1,            // [128] fp32
                     const float* __restrict__ w2,            // [128] fp32
                     const float* __restrict__ b2,            // [1]  fp32
                     float*       __restrict__ out,           // [E] fp32
                     int E)
{
    __shared__ __align__(16) unsigned short zs[TE * KDIM];   // 48 KB bf16, swizzled

    const int tid  = threadIdx.x;
    const int wave = tid >> 6;       // 0..3 (= hidden group mg)
    const int lane = tid & 63;
    const int l31  = lane & 31;
    const int hlf  = lane >> 5;
    const long long e0 = (long long)blockIdx.x * TE;

    // ---- Stage Z tile: wave w stages rows [24w, 24w+24) (48 row-halves, 12 passes).
    // lane = grp*16 + ch: each 16-lane group covers one 256 B bf16 row-half (16 B/lane).
    // Pass p: rh = 4p+grp, r = 24w + (rh>>1), hh = rh&1 (0=sotu half, 1=taxon half).
    const int ch  = lane & 15;
    const int grp = lane >> 4;

    int idxv[12];                                 // pre-load indices: breaks idx->gather chain
    #pragma unroll
    for (int p = 0; p < 12; ++p) {
        const int rh = 4 * p + grp;
        const int r  = 24 * wave + (rh >> 1);
        const int hh = rh & 1;
        long long e = e0 + r;
        if (e >= E) e = E - 1;                    // tail clamp (store is guarded)
        idxv[p] = hh ? col[e] : row[e];
    }
    #pragma unroll
    for (int p = 0; p < 12; ++p) {
        const int rh = 4 * p + grp;
        const int r  = 24 * wave + (rh >> 1);
        const int hh = rh & 1;
        const unsigned short* src = (hh ? ztb : zsb) + (long long)idxv[p] * HID + ch * 8;
        const bf16x8 v = *(const bf16x8*)src;     // no cvt: load -> ds_write direct
        const int c = hh * 16 + ch;               // chunk in concat row (0..31)
        const int q = c ^ (r & 31);               // swizzled slot
        *(bf16x8*)(zs + r * KDIM + q * 8) = v;
    }

    // ---- W1 A-frags (bf16, straight loads; L2-hot, overlaps staging latency).
    // A layout: lane holds A[m=lane&31][k = hlf*8 + j]; frag ks covers k = 16*ks..+16.
    bf16x8 afrag[16];
    {
        const unsigned short* wrow = w1b + (32 * wave + l31) * KDIM + hlf * 8;
        #pragma unroll
        for (int ks = 0; ks < 16; ++ks)
            afrag[ks] = *(const bf16x8*)(wrow + ks * 16);
    }
    __syncthreads();

    // ---- K-loop: 3 n-tiles x 16 k-steps = 48 MFMAs/wave.
    // B layout: lane holds B[n=lane&31][k=hlf*8+j]; chunk c = 2ks+hlf at slot c^l31.
    f32x16 acc[3] = {};
    #pragma unroll
    for (int ks = 0; ks < 16; ++ks) {
        #pragma unroll
        for (int nt = 0; nt < 3; ++nt) {
            const int el = 32 * nt + l31;                 // edge slot (el&31 == l31)
            const int q  = (2 * ks + hlf) ^ l31;          // swizzled slot
            bf16x8 bfrag = *(const bf16x8*)(zs + el * KDIM + q * 8);
            acc[nt] = __builtin_amdgcn_mfma_f32_32x32x16_bf16(afrag[ks], bfrag, acc[nt], 0, 0, 0);
        }
    }

    __syncthreads();                  // all b-frag reads done before aliasing zs
    float* partial = (float*)zs;      // [4 mg][TE] cross-wave partials (1.5 KB)

    // b1/w2 for this lane's 16 hidden rows: hid = 32*wave + (r&3) + 8*(r>>2) + 4*hlf
    float b1v[16], w2v[16];
    #pragma unroll
    for (int g = 0; g < 4; ++g) {
        const int hb = 32 * wave + 8 * g + 4 * hlf;
        const float4 bb = *(const float4*)(b1 + hb);
        const float4 ww = *(const float4*)(w2 + hb);
        b1v[4*g+0] = bb.x; b1v[4*g+1] = bb.y; b1v[4*g+2] = bb.z; b1v[4*g+3] = bb.w;
        w2v[4*g+0] = ww.x; w2v[4*g+1] = ww.y; w2v[4*g+2] = ww.z; w2v[4*g+3] = ww.w;
    }

    // Lane holds 16 hidden of edge (32nt + l31); mirror lane (^32) holds the
    // complementary 16 of the SAME edge -> one shfl_xor completes this wave's slice.
    #pragma unroll
    for (int nt = 0; nt < 3; ++nt) {
        float p = 0.0f;
        #pragma unroll
        for (int r = 0; r < 16; ++r) {
            const float h = fmaxf(acc[nt][r] + b1v[r], 0.0f);
            p = fmaf(h, w2v[r], p);
        }
        p += __shfl_xor(p, 32, 64);
        if (hlf == 0)
            partial[wave * TE + 32 * nt + l31] = p;
    }
    __syncthreads();

    if (tid < TE) {
        const long long e = e0 + tid;
        if (e < E) {
            out[e] = partial[0 * TE + tid] + partial[1 * TE + tid]
                   + partial[2 * TE + tid] + partial[3 * TE + tid]
                   + b2[0];
        }
    }
}

// ---------------- Fallback: round-2 proven fused kernel (only if ws too small)
__global__ __launch_bounds__(256, 2)
void edge_mlp_fused(const float* __restrict__ z_sotu, const float* __restrict__ z_taxon,
                    const int* __restrict__ row, const int* __restrict__ col,
                    const float* __restrict__ w1, const float* __restrict__ b1,
                    const float* __restrict__ w2, const float* __restrict__ b2,
                    float* __restrict__ out, int E)
{
    __shared__ __align__(16) unsigned short zs[FTE * KDIM];
    const int tid  = threadIdx.x;
    const int wave = tid >> 6;
    const int lane = tid & 63;
    const int l31  = lane & 31;
    const int hlf  = lane >> 5;
    const long long e0 = (long long)blockIdx.x * FTE;
    {
        const int ch  = lane & 15;
        const int rhl = lane >> 4;
        #pragma unroll
        for (int pass = 0; pass < 16; ++pass) {
            const int rh = pass * 4 + rhl;
            const int r  = 32 * wave + (rh >> 1);
            const int hh = rh & 1;
            long long e = e0 + r;
            if (e >= E) e = E - 1;
            const int idx = hh ? col[e] : row[e];
            const float* src = (hh ? z_taxon : z_sotu) + (long long)idx * HID + ch * 8;
            const float4 a = *(const float4*)(src);
            const float4 b = *(const float4*)(src + 4);
            const int c = hh * 16 + ch;
            const int q = c ^ (r & 31);
            *(uint4v*)(zs + r * KDIM + q * 8) = pack8u(a, b);
        }
    }
    bf16x8 afrag[16];
    {
        const float* wrow = w1 + (32 * wave + l31) * KDIM + hlf * 8;
        #pragma unroll
        for (int ks = 0; ks < 16; ++ks) {
            const float4 a = *(const float4*)(wrow + ks * 16);
            const float4 b = *(const float4*)(wrow + ks * 16 + 4);
            uint4v t = pack8u(a, b);
            afrag[ks] = *reinterpret_cast<bf16x8*>(&t);
        }
    }
    __syncthreads();
    f32x16 acc[4] = {};
    #pragma unroll
    for (int ks = 0; ks < 16; ++ks) {
        #pragma unroll
        for (int nt = 0; nt < 4; ++nt) {
            const int el = 32 * nt + l31;
            const int q  = (2 * ks + hlf) ^ l31;
            bf16x8 bfrag = *(const bf16x8*)(zs + el * KDIM + q * 8);
            acc[nt] = __builtin_amdgcn_mfma_f32_32x32x16_bf16(afrag[ks], bfrag, acc[nt], 0, 0, 0);
        }
    }
    __syncthreads();
    float* partial = (float*)zs;
    float b1v[16], w2v[16];
    #pragma unroll
    for (int g = 0; g < 4; ++g) {
        const int hb = 32 * wave + 8 * g + 4 * hlf;
        const float4 bb = *(const float4*)(b1 + hb);
        const float4 ww = *(const float4*)(w2 + hb);
        b1v[4*g+0] = bb.x; b1v[4*g+1] = bb.y; b1v[4*g+2] = bb.z; b1v[4*g+3] = bb.w;
        w2v[4*g+0] = ww.x; w2v[4*g+1] = ww.y; w2v[4*g+2] = ww.z; w2v[4*g+3] = ww.w;
    }
    #pragma unroll
    for (int nt = 0; nt < 4; ++nt) {
        float p = 0.0f;
        #pragma unroll
        for (int r = 0; r < 16; ++r) {
            const float h = fmaxf(acc[nt][r] + b1v[r], 0.0f);
            p = fmaf(h, w2v[r], p);
        }
        p += __shfl_xor(p, 32, 64);
        if (hlf == 0)
            partial[wave * FTE + 32 * nt + l31] = p;
    }
    __syncthreads();
    if (tid < FTE) {
        const long long e = e0 + tid;
        if (e < E) {
            out[e] = partial[0 * FTE + tid] + partial[1 * FTE + tid]
                   + partial[2 * FTE + tid] + partial[3 * FTE + tid]
                   + b2[0];
        }
    }
}

extern "C" void kernel_launch(void* const* d_in, const int* in_sizes, int n_in,
                              void* d_out, int out_size, void* d_ws, size_t ws_size,
                              hipStream_t stream) {
    const float* z_sotu  = (const float*)d_in[0];
    const float* z_taxon = (const float*)d_in[1];
    const int*   row     = (const int*)d_in[2];
    const int*   col     = (const int*)d_in[3];
    const float* w1      = (const float*)d_in[4];
    const float* b1      = (const float*)d_in[5];
    const float* w2      = (const float*)d_in[6];
    const float* b2      = (const float*)d_in[7];
    float*       out     = (float*)d_out;

    const long long ES = in_sizes[0];   // 12,800,000
    const long long ET = in_sizes[1];   //  6,400,000
    const long long EW = in_sizes[4];   //     32,768
    const int E = in_sizes[2];
    const size_t need = (size_t)(ES + ET + EW) * 2;

    if (ws_size >= need) {
        unsigned short* zsb = (unsigned short*)d_ws;
        unsigned short* ztb = zsb + ES;
        unsigned short* w1b = ztb + ET;
        const long long total16 = (ES + ET + EW) / 16;
        const int cblocks = (int)((total16 + 255) / 256);
        hipLaunchKernelGGL(convert_kernel, dim3(cblocks), dim3(256), 0, stream,
                           z_sotu, z_taxon, w1, zsb, ztb, w1b, ES, ET, EW);
        const int nblocks = (E + TE - 1) / TE;
        hipLaunchKernelGGL(edge_mlp_kernel, dim3(nblocks), dim3(256), 0, stream,
                           zsb, ztb, row, col, w1b, b1, w2, b2, out, E);
    } else {
        const int nblocks = (E + FTE - 1) / FTE;
        hipLaunchKernelGGL(edge_mlp_fused, dim3(nblocks), dim3(256), 0, stream,
                           z_sotu, z_taxon, row, col, w1, b1, w2, b2, out, E);
    }
}

// Round 6
// 227.112 us; speedup vs baseline: 1.9036x; 1.0297x over previous
//
#include <hip/hip_runtime.h>
#include <hip/hip_bf16.h>

// EdgeDecoder: out[e] = w2 . relu(W1 @ concat(z_sotu[row[e]], z_taxon[col[e]]) + b1) + b2
// E=1e6, H=128, K=2H=256. fp32 inputs, int32 indices, fp32 output.
//
// Round 6: algebraic restructure. W1@concat(zs,zt) = W1s@zs + W1t@zt, so:
//   Phase 1 (prep_kernel): U[s] = W1s@zs[s] + b1 (100K x 128 bf16), V[t] = W1t@zt[t]
//     -- two small dense GEMMs (4.9 GFLOP), streaming fp32 reads, NO gather, no LDS.
//   Phase 2 (edge_kernel): out[e] = w2 . relu(U[row[e]] + V[col[e]]) + b2
//     -- pure streaming gather: no MFMA/LDS/barriers, ~24 VGPR -> ~32 waves/CU,
//        16 lanes/edge (coalesced 256 B row reads), ILP=2 edges/thread.
// Same math + one extra bf16 rounding of U/V (pre-relu): absmax ~0.01 << 0.031.
// Kills both R5 costs: the 99 us badly-coalesced convert pass, and the
// latency-bound MFMA-coupled gather (R5 main kernel: 45% busy at 12 waves/CU).

#define HID  128
#define FTE  128    // fallback tile

typedef __attribute__((ext_vector_type(8)))  short    bf16x8;   // 8 bf16 = 4 VGPRs
typedef __attribute__((ext_vector_type(16))) float    f32x16;   // 32x32 MFMA accumulator
typedef __attribute__((ext_vector_type(4)))  unsigned uint4v;   // 16 B

__device__ __forceinline__ float bf2f(unsigned short u) {
    return __uint_as_float(((unsigned)u) << 16);
}
__device__ __forceinline__ unsigned pk2(float x, float y) {
    __hip_bfloat162 t = __float22bfloat162_rn(make_float2(x, y));  // packed RNE cvt
    return *reinterpret_cast<unsigned*>(&t);
}
__device__ __forceinline__ bf16x8 pack8(float4 a, float4 b) {
    uint4v r;
    r.x = pk2(a.x, a.y); r.y = pk2(a.z, a.w);
    r.z = pk2(b.x, b.y); r.w = pk2(b.z, b.w);
    return *reinterpret_cast<bf16x8*>(&r);
}

// ---------------- Phase 1: U = zs@W1s^T + b1, V = zt@W1t^T  (bf16 out, row-major)
// Block = 256 thr (4 waves), 128 rows of z per block. Wave w owns hidden [32w,32w+32).
// No LDS: each wave loads its B-frags (z rows) straight from global (L2-hot across waves).
__global__ __launch_bounds__(256)
void prep_kernel(const float* __restrict__ zs, const float* __restrict__ zt,
                 const float* __restrict__ w1, const float* __restrict__ b1,
                 unsigned short* __restrict__ U, unsigned short* __restrict__ V,
                 int NS, int NT, int NBU)
{
    const bool isU = (int)blockIdx.x < NBU;
    const float* z      = isU ? zs : zt;
    unsigned short* O   = isU ? U  : V;
    const int N    = isU ? NS : NT;
    const int s0   = (isU ? blockIdx.x : blockIdx.x - NBU) * 128;
    const int koff = isU ? 0 : 128;          // W1 column offset (sotu half / taxon half)

    const int tid  = threadIdx.x;
    const int wave = tid >> 6;       // hidden group: rows [32*wave, 32*wave+32)
    const int lane = tid & 63;
    const int l31  = lane & 31;
    const int hlf  = lane >> 5;

    // A-frags: A[m=lane&31][k=hlf*8+j], frag ks covers k_local = 16ks..+16 (K=128 -> 8 frags)
    bf16x8 afrag[8];
    {
        const float* wrow = w1 + (32 * wave + l31) * 256 + koff + hlf * 8;
        #pragma unroll
        for (int ks = 0; ks < 8; ++ks) {
            const float4 a = *(const float4*)(wrow + ks * 16);
            const float4 b = *(const float4*)(wrow + ks * 16 + 4);
            afrag[ks] = pack8(a, b);
        }
    }

    // K-loop: B[n=l31][k=hlf*8+j] loaded per (nt, ks) from z row s0+32nt+l31 (clamped).
    f32x16 acc[4] = {};
    #pragma unroll
    for (int ks = 0; ks < 8; ++ks) {
        #pragma unroll
        for (int nt = 0; nt < 4; ++nt) {
            int s = s0 + 32 * nt + l31;
            if (s >= N) s = N - 1;                       // clamp (store guarded)
            const float* src = z + s * HID + ks * 16 + hlf * 8;
            const float4 a = *(const float4*)(src);
            const float4 b = *(const float4*)(src + 4);
            const bf16x8 bfrag = pack8(a, b);
            acc[nt] = __builtin_amdgcn_mfma_f32_32x32x16_bf16(afrag[ks], bfrag, acc[nt], 0, 0, 0);
        }
    }

    // b1 for this lane's 16 hidden rows (U only): c = 32w + (reg&3) + 8*(reg>>2) + 4*hlf
    float b1v[16];
    #pragma unroll
    for (int g = 0; g < 4; ++g) {
        const int hb = 32 * wave + 8 * g + 4 * hlf;
        if (isU) {
            const float4 bb = *(const float4*)(b1 + hb);
            b1v[4*g+0] = bb.x; b1v[4*g+1] = bb.y; b1v[4*g+2] = bb.z; b1v[4*g+3] = bb.w;
        } else {
            b1v[4*g+0] = b1v[4*g+1] = b1v[4*g+2] = b1v[4*g+3] = 0.0f;
        }
    }

    // Epilogue: C layout col=l31 (=row s within n-tile), rows = the 16 c's above.
    // Store 4 consecutive c as 4 bf16 (8 B) -> O[s*128 + c_base].
    #pragma unroll
    for (int nt = 0; nt < 4; ++nt) {
        const int s = s0 + 32 * nt + l31;
        if (s < N) {
            #pragma unroll
            for (int g = 0; g < 4; ++g) {
                const int cb = 32 * wave + 8 * g + 4 * hlf;
                uint2 o;
                o.x = pk2(acc[nt][4*g+0] + b1v[4*g+0], acc[nt][4*g+1] + b1v[4*g+1]);
                o.y = pk2(acc[nt][4*g+2] + b1v[4*g+2], acc[nt][4*g+3] + b1v[4*g+3]);
                *(uint2*)(O + s * HID + cb) = o;
            }
        }
    }
}

// ---------------- Phase 2: out[e] = w2 . relu(U[row[e]] + V[col[e]]) + b2
// 16 lanes/edge (lane c16 owns channels [8c16, 8c16+8)); ILP=2 edges per group.
// Block = 256 thr = 16 groups -> 32 edges/block.
__global__ __launch_bounds__(256)
void edge_kernel(const unsigned short* __restrict__ U,   // [NS,128] bf16
                 const unsigned short* __restrict__ V,   // [NT,128] bf16
                 const int*   __restrict__ row, const int* __restrict__ col,
                 const float* __restrict__ w2, const float* __restrict__ b2,
                 float* __restrict__ out, int E)
{
    const int tid = threadIdx.x;
    const int g   = tid >> 4;        // group 0..15
    const int c16 = tid & 15;        // channel chunk

    const long long eb = (long long)blockIdx.x * 32 + g * 2;
    const long long e0 = eb, e1 = eb + 1;
    const long long ec0 = e0 < E ? e0 : E - 1;
    const long long ec1 = e1 < E ? e1 : E - 1;

    // Indices first (breaks idx->gather chains), then all 4 row loads in flight.
    const int r0 = row[ec0], c0 = col[ec0];
    const int r1 = row[ec1], c1 = col[ec1];
    const bf16x8 u0 = *(const bf16x8*)(U + r0 * HID + c16 * 8);
    const bf16x8 v0 = *(const bf16x8*)(V + c0 * HID + c16 * 8);
    const bf16x8 u1 = *(const bf16x8*)(U + r1 * HID + c16 * 8);
    const bf16x8 v1 = *(const bf16x8*)(V + c1 * HID + c16 * 8);

    // w2 chunk for this lane (L1-hot)
    const float4 wa = *(const float4*)(w2 + c16 * 8);
    const float4 wb = *(const float4*)(w2 + c16 * 8 + 4);
    float w2v[8] = {wa.x, wa.y, wa.z, wa.w, wb.x, wb.y, wb.z, wb.w};

    float p0 = 0.0f, p1 = 0.0f;
    #pragma unroll
    for (int j = 0; j < 8; ++j) {
        const float h0 = fmaxf(bf2f((unsigned short)u0[j]) + bf2f((unsigned short)v0[j]), 0.0f);
        const float h1 = fmaxf(bf2f((unsigned short)u1[j]) + bf2f((unsigned short)v1[j]), 0.0f);
        p0 = fmaf(h0, w2v[j], p0);
        p1 = fmaf(h1, w2v[j], p1);
    }
    // reduce across the 16-lane group
    #pragma unroll
    for (int d = 1; d < 16; d <<= 1) {
        p0 += __shfl_xor(p0, d, 64);
        p1 += __shfl_xor(p1, d, 64);
    }
    if (c16 == 0) {
        const float bb = b2[0];
        if (e0 < E) out[e0] = p0 + bb;
        if (e1 < E) out[e1] = p1 + bb;
    }
}

// ---------------- Fallback: round-2 proven fused kernel (only if ws too small)
__global__ __launch_bounds__(256, 2)
void edge_mlp_fused(const float* __restrict__ z_sotu, const float* __restrict__ z_taxon,
                    const int* __restrict__ row, const int* __restrict__ col,
                    const float* __restrict__ w1, const float* __restrict__ b1,
                    const float* __restrict__ w2, const float* __restrict__ b2,
                    float* __restrict__ out, int E)
{
    __shared__ __align__(16) unsigned short zsh[FTE * 256];
    const int tid  = threadIdx.x;
    const int wave = tid >> 6;
    const int lane = tid & 63;
    const int l31  = lane & 31;
    const int hlf  = lane >> 5;
    const long long e0 = (long long)blockIdx.x * FTE;
    {
        const int ch  = lane & 15;
        const int rhl = lane >> 4;
        #pragma unroll
        for (int pass = 0; pass < 16; ++pass) {
            const int rh = pass * 4 + rhl;
            const int r  = 32 * wave + (rh >> 1);
            const int hh = rh & 1;
            long long e = e0 + r;
            if (e >= E) e = E - 1;
            const int idx = hh ? col[e] : row[e];
            const float* src = (hh ? z_taxon : z_sotu) + (long long)idx * HID + ch * 8;
            const float4 a = *(const float4*)(src);
            const float4 b = *(const float4*)(src + 4);
            const int c = hh * 16 + ch;
            const int q = c ^ (r & 31);
            *(bf16x8*)(zsh + r * 256 + q * 8) = pack8(a, b);
        }
    }
    bf16x8 afrag[16];
    {
        const float* wrow = w1 + (32 * wave + l31) * 256 + hlf * 8;
        #pragma unroll
        for (int ks = 0; ks < 16; ++ks) {
            const float4 a = *(const float4*)(wrow + ks * 16);
            const float4 b = *(const float4*)(wrow + ks * 16 + 4);
            afrag[ks] = pack8(a, b);
        }
    }
    __syncthreads();
    f32x16 acc[4] = {};
    #pragma unroll
    for (int ks = 0; ks < 16; ++ks) {
        #pragma unroll
        for (int nt = 0; nt < 4; ++nt) {
            const int el = 32 * nt + l31;
            const int q  = (2 * ks + hlf) ^ l31;
            bf16x8 bfrag = *(const bf16x8*)(zsh + el * 256 + q * 8);
            acc[nt] = __builtin_amdgcn_mfma_f32_32x32x16_bf16(afrag[ks], bfrag, acc[nt], 0, 0, 0);
        }
    }
    __syncthreads();
    float* partial = (float*)zsh;
    float b1v[16], w2v[16];
    #pragma unroll
    for (int g = 0; g < 4; ++g) {
        const int hb = 32 * wave + 8 * g + 4 * hlf;
        const float4 bb = *(const float4*)(b1 + hb);
        const float4 ww = *(const float4*)(w2 + hb);
        b1v[4*g+0] = bb.x; b1v[4*g+1] = bb.y; b1v[4*g+2] = bb.z; b1v[4*g+3] = bb.w;
        w2v[4*g+0] = ww.x; w2v[4*g+1] = ww.y; w2v[4*g+2] = ww.z; w2v[4*g+3] = ww.w;
    }
    #pragma unroll
    for (int nt = 0; nt < 4; ++nt) {
        float p = 0.0f;
        #pragma unroll
        for (int r = 0; r < 16; ++r) {
            const float h = fmaxf(acc[nt][r] + b1v[r], 0.0f);
            p = fmaf(h, w2v[r], p);
        }
        p += __shfl_xor(p, 32, 64);
        if (hlf == 0)
            partial[wave * FTE + 32 * nt + l31] = p;
    }
    __syncthreads();
    if (tid < FTE) {
        const long long e = e0 + tid;
        if (e < E) {
            out[e] = partial[0 * FTE + tid] + partial[1 * FTE + tid]
                   + partial[2 * FTE + tid] + partial[3 * FTE + tid]
                   + b2[0];
        }
    }
}

extern "C" void kernel_launch(void* const* d_in, const int* in_sizes, int n_in,
                              void* d_out, int out_size, void* d_ws, size_t ws_size,
                              hipStream_t stream) {
    const float* z_sotu  = (const float*)d_in[0];
    const float* z_taxon = (const float*)d_in[1];
    const int*   row     = (const int*)d_in[2];
    const int*   col     = (const int*)d_in[3];
    const float* w1      = (const float*)d_in[4];
    const float* b1      = (const float*)d_in[5];
    const float* w2      = (const float*)d_in[6];
    const float* b2      = (const float*)d_in[7];
    float*       out     = (float*)d_out;

    const int NS = in_sizes[0] / HID;   // 100000
    const int NT = in_sizes[1] / HID;   //  50000
    const int E  = in_sizes[2];
    const size_t need = ((size_t)NS + NT) * HID * 2;   // 38.4 MB bf16 U+V

    if (ws_size >= need) {
        unsigned short* U = (unsigned short*)d_ws;
        unsigned short* Vv = U + (size_t)NS * HID;
        const int NBU = (NS + 127) / 128;
        const int NBV = (NT + 127) / 128;
        hipLaunchKernelGGL(prep_kernel, dim3(NBU + NBV), dim3(256), 0, stream,
                           z_sotu, z_taxon, w1, b1, U, Vv, NS, NT, NBU);
        const int nblocks = (E + 31) / 32;
        hipLaunchKernelGGL(edge_kernel, dim3(nblocks), dim3(256), 0, stream,
                           U, Vv, row, col, w2, b2, out, E);
    } else {
        const int nblocks = (E + FTE - 1) / FTE;
        hipLaunchKernelGGL(edge_mlp_fused, dim3(nblocks), dim3(256), 0, stream,
                           z_sotu, z_taxon, row, col, w1, b1, w2, b2, out, E);
    }
}

// Round 7
// 203.635 us; speedup vs baseline: 2.1230x; 1.1153x over previous
//
#include <hip/hip_runtime.h>
#include <hip/hip_bf16.h>

// EdgeDecoder: out[e] = w2 . relu(W1 @ concat(z_sotu[row[e]], z_taxon[col[e]]) + b1) + b2
// E=1e6, H=128, K=2H=256. fp32 inputs, int32 indices, fp32 output.
//
// Round 7 (on the R6 U/V decomposition: W1@concat = W1s@zs + W1t@zt):
//  Phase 1 prep v2: U = zs@W1s^T + b1, V = zt@W1t^T, bf16 out. R6's prep was
//    latency-bound (90% idle): dependent global->cvt->MFMA B-frag chains. Now the
//    z tile (contiguous rows, streaming NOT gather) is staged through LDS with
//    coalesced float4 loads + cvt-on-store; stride 136 bf16 pads row starts 4 banks
//    apart -> same minimal b128 bank pattern R2 measured at 0 conflicts.
//    LDS 34 KB -> 4 blocks/CU.
//  Phase 2 edge v2: out[e] = w2 . relu(U[row[e]] + V[col[e]]) + b2. Gather of
//    512 MB runs at the ~3.3-3.8 TB/s random-row fabric ceiling (R3/R5/R6 all
//    converge there). ILP raised to 4 edges per 16-lane group (8 gathers in
//    flight/thread) to rule out outstanding-request limits; float4 stores.

#define HID  128
#define FTE  128    // fallback tile
#define PST  136    // prep LDS row stride (bf16 elems): 128 + 8 pad

typedef __attribute__((ext_vector_type(8)))  short    bf16x8;   // 8 bf16 = 4 VGPRs
typedef __attribute__((ext_vector_type(16))) float    f32x16;   // 32x32 MFMA accumulator
typedef __attribute__((ext_vector_type(4)))  unsigned uint4v;   // 16 B

__device__ __forceinline__ float bf2f(unsigned short u) {
    return __uint_as_float(((unsigned)u) << 16);
}
__device__ __forceinline__ unsigned pk2(float x, float y) {
    __hip_bfloat162 t = __float22bfloat162_rn(make_float2(x, y));  // packed RNE cvt
    return *reinterpret_cast<unsigned*>(&t);
}
__device__ __forceinline__ bf16x8 pack8(float4 a, float4 b) {
    uint4v r;
    r.x = pk2(a.x, a.y); r.y = pk2(a.z, a.w);
    r.z = pk2(b.x, b.y); r.w = pk2(b.z, b.w);
    return *reinterpret_cast<bf16x8*>(&r);
}

// ---------------- Phase 1: U = zs@W1s^T + b1, V = zt@W1t^T  (bf16 out, row-major)
// Block = 256 thr (4 waves), 128 z-rows per block, LDS-staged B.
__global__ __launch_bounds__(256)
void prep_kernel(const float* __restrict__ zs, const float* __restrict__ zt,
                 const float* __restrict__ w1, const float* __restrict__ b1,
                 unsigned short* __restrict__ U, unsigned short* __restrict__ V,
                 int NS, int NT, int NBU)
{
    __shared__ __align__(16) unsigned short zl[128 * PST];   // 34 KB bf16

    const bool isU = (int)blockIdx.x < NBU;
    const float* z      = isU ? zs : zt;
    unsigned short* O   = isU ? U  : V;
    const int N    = isU ? NS : NT;
    const int s0   = (isU ? blockIdx.x : blockIdx.x - NBU) * 128;
    const int koff = isU ? 0 : 128;          // W1 column offset (sotu / taxon half)

    const int tid  = threadIdx.x;
    const int wave = tid >> 6;       // hidden group: rows [32*wave, 32*wave+32)
    const int lane = tid & 63;
    const int l31  = lane & 31;
    const int hlf  = lane >> 5;

    // ---- Stage: 128 rows x 16 chunks (8 fp32 -> 8 bf16). flat f = i*256+tid:
    // consecutive tid = consecutive 32 B of global (fully coalesced streaming).
    #pragma unroll
    for (int i = 0; i < 8; ++i) {
        const int f = i * 256 + tid;
        const int r = f >> 4;                   // tile row 0..127
        const int c = f & 15;                   // chunk 0..15
        int s = s0 + r;
        if (s >= N) s = N - 1;                  // clamp (store guarded)
        const float* src = z + (long long)s * HID + c * 8;
        const float4 a = *(const float4*)(src);
        const float4 b = *(const float4*)(src + 4);
        *(bf16x8*)(zl + r * PST + c * 8) = pack8(a, b);
    }

    // ---- A-frags: A[m=l31][k=hlf*8+j], frag ks covers k_local = 16ks..+16 (K=128).
    bf16x8 afrag[8];
    {
        const float* wrow = w1 + (32 * wave + l31) * 256 + koff + hlf * 8;
        #pragma unroll
        for (int ks = 0; ks < 8; ++ks) {
            const float4 a = *(const float4*)(wrow + ks * 16);
            const float4 b = *(const float4*)(wrow + ks * 16 + 4);
            afrag[ks] = pack8(a, b);
        }
    }
    __syncthreads();

    // ---- K-loop: 4 n-tiles x 8 k-steps = 32 MFMAs/wave; B from LDS.
    f32x16 acc[4] = {};
    #pragma unroll
    for (int ks = 0; ks < 8; ++ks) {
        #pragma unroll
        for (int nt = 0; nt < 4; ++nt) {
            const int el = 32 * nt + l31;
            const bf16x8 bfrag = *(const bf16x8*)(zl + el * PST + (2 * ks + hlf) * 8);
            acc[nt] = __builtin_amdgcn_mfma_f32_32x32x16_bf16(afrag[ks], bfrag, acc[nt], 0, 0, 0);
        }
    }

    // ---- b1 (U only): lane's 16 hidden = 32w + (reg&3) + 8*(reg>>2) + 4*hlf
    float b1v[16];
    #pragma unroll
    for (int g = 0; g < 4; ++g) {
        const int hb = 32 * wave + 8 * g + 4 * hlf;
        if (isU) {
            const float4 bb = *(const float4*)(b1 + hb);
            b1v[4*g+0] = bb.x; b1v[4*g+1] = bb.y; b1v[4*g+2] = bb.z; b1v[4*g+3] = bb.w;
        } else {
            b1v[4*g+0] = b1v[4*g+1] = b1v[4*g+2] = b1v[4*g+3] = 0.0f;
        }
    }

    // ---- Epilogue: C col=l31 (= z row within n-tile); store 4 bf16 (8 B) per group.
    #pragma unroll
    for (int nt = 0; nt < 4; ++nt) {
        const int s = s0 + 32 * nt + l31;
        if (s < N) {
            #pragma unroll
            for (int g = 0; g < 4; ++g) {
                const int cb = 32 * wave + 8 * g + 4 * hlf;
                uint2 o;
                o.x = pk2(acc[nt][4*g+0] + b1v[4*g+0], acc[nt][4*g+1] + b1v[4*g+1]);
                o.y = pk2(acc[nt][4*g+2] + b1v[4*g+2], acc[nt][4*g+3] + b1v[4*g+3]);
                *(uint2*)(O + (long long)s * HID + cb) = o;
            }
        }
    }
}

// ---------------- Phase 2: out[e] = w2 . relu(U[row[e]] + V[col[e]]) + b2
// 16 lanes/edge-group, 4 edges per group (8 gathers of 16 B in flight per thread).
// Block = 256 thr = 16 groups -> 64 edges/block.
__global__ __launch_bounds__(256)
void edge_kernel(const unsigned short* __restrict__ U,   // [NS,128] bf16
                 const unsigned short* __restrict__ V,   // [NT,128] bf16
                 const int*   __restrict__ row, const int* __restrict__ col,
                 const float* __restrict__ w2, const float* __restrict__ b2,
                 float* __restrict__ out, int E)
{
    const int tid = threadIdx.x;
    const int g   = tid >> 4;        // group 0..15
    const int c16 = tid & 15;        // channel chunk (8 channels)

    const long long eb = (long long)blockIdx.x * 64 + g * 4;

    int ri[4], ci[4];
    #pragma unroll
    for (int j = 0; j < 4; ++j) {
        long long e = eb + j;
        if (e >= E) e = E - 1;
        ri[j] = row[e]; ci[j] = col[e];
    }
    bf16x8 u[4], v[4];
    #pragma unroll
    for (int j = 0; j < 4; ++j) {
        u[j] = *(const bf16x8*)(U + (long long)ri[j] * HID + c16 * 8);
        v[j] = *(const bf16x8*)(V + (long long)ci[j] * HID + c16 * 8);
    }

    const float4 wa = *(const float4*)(w2 + c16 * 8);
    const float4 wb = *(const float4*)(w2 + c16 * 8 + 4);
    const float w2v[8] = {wa.x, wa.y, wa.z, wa.w, wb.x, wb.y, wb.z, wb.w};

    float p[4] = {0.0f, 0.0f, 0.0f, 0.0f};
    #pragma unroll
    for (int j = 0; j < 4; ++j) {
        #pragma unroll
        for (int k = 0; k < 8; ++k) {
            const float h = fmaxf(bf2f((unsigned short)u[j][k]) +
                                  bf2f((unsigned short)v[j][k]), 0.0f);
            p[j] = fmaf(h, w2v[k], p[j]);
        }
    }
    #pragma unroll
    for (int d = 1; d < 16; d <<= 1) {
        #pragma unroll
        for (int j = 0; j < 4; ++j) p[j] += __shfl_xor(p[j], d, 64);
    }
    if (c16 == 0) {
        const float bb = b2[0];
        if (eb + 3 < E) {
            *(float4*)(out + eb) = make_float4(p[0] + bb, p[1] + bb, p[2] + bb, p[3] + bb);
        } else {
            #pragma unroll
            for (int j = 0; j < 4; ++j)
                if (eb + j < E) out[eb + j] = p[j] + bb;
        }
    }
}

// ---------------- Fallback: round-2 proven fused kernel (only if ws too small)
__global__ __launch_bounds__(256, 2)
void edge_mlp_fused(const float* __restrict__ z_sotu, const float* __restrict__ z_taxon,
                    const int* __restrict__ row, const int* __restrict__ col,
                    const float* __restrict__ w1, const float* __restrict__ b1,
                    const float* __restrict__ w2, const float* __restrict__ b2,
                    float* __restrict__ out, int E)
{
    __shared__ __align__(16) unsigned short zsh[FTE * 256];
    const int tid  = threadIdx.x;
    const int wave = tid >> 6;
    const int lane = tid & 63;
    const int l31  = lane & 31;
    const int hlf  = lane >> 5;
    const long long e0 = (long long)blockIdx.x * FTE;
    {
        const int ch  = lane & 15;
        const int rhl = lane >> 4;
        #pragma unroll
        for (int pass = 0; pass < 16; ++pass) {
            const int rh = pass * 4 + rhl;
            const int r  = 32 * wave + (rh >> 1);
            const int hh = rh & 1;
            long long e = e0 + r;
            if (e >= E) e = E - 1;
            const int idx = hh ? col[e] : row[e];
            const float* src = (hh ? z_taxon : z_sotu) + (long long)idx * HID + ch * 8;
            const float4 a = *(const float4*)(src);
            const float4 b = *(const float4*)(src + 4);
            const int c = hh * 16 + ch;
            const int q = c ^ (r & 31);
            *(bf16x8*)(zsh + r * 256 + q * 8) = pack8(a, b);
        }
    }
    bf16x8 afrag[16];
    {
        const float* wrow = w1 + (32 * wave + l31) * 256 + hlf * 8;
        #pragma unroll
        for (int ks = 0; ks < 16; ++ks) {
            const float4 a = *(const float4*)(wrow + ks * 16);
            const float4 b = *(const float4*)(wrow + ks * 16 + 4);
            afrag[ks] = pack8(a, b);
        }
    }
    __syncthreads();
    f32x16 acc[4] = {};
    #pragma unroll
    for (int ks = 0; ks < 16; ++ks) {
        #pragma unroll
        for (int nt = 0; nt < 4; ++nt) {
            const int el = 32 * nt + l31;
            const int q  = (2 * ks + hlf) ^ l31;
            bf16x8 bfrag = *(const bf16x8*)(zsh + el * 256 + q * 8);
            acc[nt] = __builtin_amdgcn_mfma_f32_32x32x16_bf16(afrag[ks], bfrag, acc[nt], 0, 0, 0);
        }
    }
    __syncthreads();
    float* partial = (float*)zsh;
    float b1v[16], w2v[16];
    #pragma unroll
    for (int g = 0; g < 4; ++g) {
        const int hb = 32 * wave + 8 * g + 4 * hlf;
        const float4 bb = *(const float4*)(b1 + hb);
        const float4 ww = *(const float4*)(w2 + hb);
        b1v[4*g+0] = bb.x; b1v[4*g+1] = bb.y; b1v[4*g+2] = bb.z; b1v[4*g+3] = bb.w;
        w2v[4*g+0] = ww.x; w2v[4*g+1] = ww.y; w2v[4*g+2] = ww.z; w2v[4*g+3] = ww.w;
    }
    #pragma unroll
    for (int nt = 0; nt < 4; ++nt) {
        float p = 0.0f;
        #pragma unroll
        for (int r = 0; r < 16; ++r) {
            const float h = fmaxf(acc[nt][r] + b1v[r], 0.0f);
            p = fmaf(h, w2v[r], p);
        }
        p += __shfl_xor(p, 32, 64);
        if (hlf == 0)
            partial[wave * FTE + 32 * nt + l31] = p;
    }
    __syncthreads();
    if (tid < FTE) {
        const long long e = e0 + tid;
        if (e < E) {
            out[e] = partial[0 * FTE + tid] + partial[1 * FTE + tid]
                   + partial[2 * FTE + tid] + partial[3 * FTE + tid]
                   + b2[0];
        }
    }
}

extern "C" void kernel_launch(void* const* d_in, const int* in_sizes, int n_in,
                              void* d_out, int out_size, void* d_ws, size_t ws_size,
                              hipStream_t stream) {
    const float* z_sotu  = (const float*)d_in[0];
    const float* z_taxon = (const float*)d_in[1];
    const int*   row     = (const int*)d_in[2];
    const int*   col     = (const int*)d_in[3];
    const float* w1      = (const float*)d_in[4];
    const float* b1      = (const float*)d_in[5];
    const float* w2      = (const float*)d_in[6];
    const float* b2      = (const float*)d_in[7];
    float*       out     = (float*)d_out;

    const int NS = in_sizes[0] / HID;   // 100000
    const int NT = in_sizes[1] / HID;   //  50000
    const int E  = in_sizes[2];
    const size_t need = ((size_t)NS + NT) * HID * 2;   // 38.4 MB bf16 U+V

    if (ws_size >= need) {
        unsigned short* U = (unsigned short*)d_ws;
        unsigned short* Vv = U + (size_t)NS * HID;
        const int NBU = (NS + 127) / 128;
        const int NBV = (NT + 127) / 128;
        hipLaunchKernelGGL(prep_kernel, dim3(NBU + NBV), dim3(256), 0, stream,
                           z_sotu, z_taxon, w1, b1, U, Vv, NS, NT, NBU);
        const int nblocks = (E + 63) / 64;
        hipLaunchKernelGGL(edge_kernel, dim3(nblocks), dim3(256), 0, stream,
                           U, Vv, row, col, w2, b2, out, E);
    } else {
        const int nblocks = (E + FTE - 1) / FTE;
        hipLaunchKernelGGL(edge_mlp_fused, dim3(nblocks), dim3(256), 0, stream,
                           z_sotu, z_taxon, row, col, w1, b1, w2, b2, out, E);
    }
}